// Round 2
// baseline (10704.666 us; speedup 1.0000x reference)
//
#include <hip/hip_runtime.h>
#include <hip/hip_bf16.h>
#include <hip/hip_cooperative_groups.h>

#define D 768
#define BB 32
#define XX 256
#define CH 3816   // vocab chunk per fin tile (8 chunks cover 30522)
#define NLG 128   // attn logit tiles (scheduled first in mid phase)

namespace cg = cooperative_groups;

typedef __bf16 bf16x8 __attribute__((ext_vector_type(8)));
typedef float  f32x4  __attribute__((ext_vector_type(4)));

// ---------------------------------------------------------------------------
// shared-memory unions (persistent kernel reuses one allocation per phase)
// ---------------------------------------------------------------------------
struct __align__(16) GS { float vec[BB][132]; int tokl[BB]; };
struct __align__(16) CS { float part[8][32]; };
struct __align__(16) MS { float sh[64][33]; float dsum[32]; };
struct __align__(16) FS { float pctx[CH]; float red[256]; float aw[256];
                          unsigned long long wmax[4]; };
union  __align__(16) SMU { GS g; CS c; MS m; FS f; };

// ---------------------------------------------------------------------------
// phase bodies (shared between persistent mega-kernel and fallback kernels)
// ---------------------------------------------------------------------------
__device__ __forceinline__ void cvt_item(const float* __restrict__ src,
                                         __bf16* __restrict__ dst, int i)
{
    float4 f0 = *(const float4*)(src + (size_t)i * 8);
    float4 f1 = *(const float4*)(src + (size_t)i * 8 + 4);
    bf16x8 o;
    o[0] = (__bf16)f0.x; o[1] = (__bf16)f0.y; o[2] = (__bf16)f0.z; o[3] = (__bf16)f0.w;
    o[4] = (__bf16)f1.x; o[5] = (__bf16)f1.y; o[6] = (__bf16)f1.z; o[7] = (__bf16)f1.w;
    *(bf16x8*)(dst + (size_t)i * 8) = o;
}

__device__ __forceinline__ void penc_tile(int tile, int t,
    const float* __restrict__ enc, const float* __restrict__ wgen,
    float* __restrict__ penc)
{
    const int b = tile >> 2, c = tile & 3;
    const int x0 = c * 64;
    const int l = t & 31;
    float4 wr[6];
    #pragma unroll
    for (int p = 0; p < 6; ++p)
        wr[p] = *(const float4*)(wgen + 1536 + l * 4 + p * 128);
    for (int g = 0; g < 8; ++g) {
        int x = x0 + g * 8 + (t >> 5);
        const float* er = enc + ((size_t)b * XX + x) * D + l * 4;
        float acc = 0.f;
        #pragma unroll
        for (int p = 0; p < 6; ++p) {
            float4 e = *(const float4*)(er + p * 128);
            acc += e.x * wr[p].x + e.y * wr[p].y + e.z * wr[p].z + e.w * wr[p].w;
        }
        #pragma unroll
        for (int m = 1; m <= 16; m <<= 1) acc += __shfl_xor(acc, m);
        if (l == 0) penc[b * XX + x] = acc;
    }
}

__device__ __forceinline__ void set_tokl(int t, int* tokl,
    const unsigned long long* __restrict__ toks)
{
    if (t < 32)
        tokl[t] = toks ? (int)(0xFFFFFFFFu - (unsigned)(toks[t] & 0xFFFFFFFFull)) : 0;
}

__device__ __forceinline__ void gates_tile(int tile, int t,
    float (*vec)[132], const int* tokl, bool useTok,
    const float* __restrict__ xbase, long xbstride,
    const float* __restrict__ hin,
    const float* __restrict__ wih, const float* __restrict__ whh,
    float* __restrict__ gT)
{
    const int b = t & 31, rl = t >> 5;
    const int rglob = tile * 8 + rl;
    const bool isH = rglob >= 2304;
    const int row = isH ? rglob - 2304 : rglob;
    const float* w = (isH ? whh : wih) + (size_t)row * D;

    float acc = 0.f;
    for (int c = 0; c < 6; ++c) {
        const int kc = c * 128;
        __syncthreads();
        for (int p = 0; p < 4; ++p) {
            int fid = t + 256 * p;
            int bb = fid >> 5, k4 = (fid & 31) * 4;
            const float* src;
            if (isH) src = hin + (size_t)bb * D;
            else     src = useTok ? (xbase + (size_t)tokl[bb] * D)
                                  : (xbase + (size_t)bb * xbstride);
            *(float4*)&vec[bb][k4] = *(const float4*)(src + kc + k4);
        }
        __syncthreads();
        #pragma unroll
        for (int k4 = 0; k4 < 128; k4 += 4) {
            float4 wv = *(const float4*)(w + kc + k4);
            float4 xv = *(const float4*)&vec[b][k4];
            acc += wv.x * xv.x + wv.y * xv.y + wv.z * xv.z + wv.w * xv.w;
        }
    }
    gT[(size_t)rglob * 32 + b] = acc;
}

__device__ __forceinline__ void comb_tile(int tile, int t, float (*part)[32],
    const float* __restrict__ gT,
    const float* __restrict__ bih, const float* __restrict__ bhh,
    const float* __restrict__ hin,
    const float* __restrict__ xbase, long xbstride,
    const unsigned long long* __restrict__ toks,
    const float* __restrict__ wgen,
    float* __restrict__ hout, __bf16* __restrict__ hbf,
    float* __restrict__ pgen_part,
    unsigned long long* __restrict__ argz)
{
    const int b = t & 31, dl = t >> 5;
    const int d = tile * 8 + dl;
    if (tile == 0 && t < 32) argz[t] = 0ULL;
    float ir = gT[(size_t)d * 32 + b]            + bih[d];
    float iz = gT[(size_t)(768 + d) * 32 + b]    + bih[768 + d];
    float in_ = gT[(size_t)(1536 + d) * 32 + b]  + bih[1536 + d];
    float hr = gT[(size_t)(2304 + d) * 32 + b]   + bhh[d];
    float hz = gT[(size_t)(3072 + d) * 32 + b]   + bhh[768 + d];
    float hn = gT[(size_t)(3840 + d) * 32 + b]   + bhh[1536 + d];
    float r = 1.0f / (1.0f + expf(-(ir + hr)));
    float z = 1.0f / (1.0f + expf(-(iz + hz)));
    float n = tanhf(in_ + r * hn);
    float hold = hin[(size_t)b * D + d];
    float hv = (1.0f - z) * n + z * hold;
    hout[(size_t)b * D + d] = hv;
    hbf[(size_t)b * D + d] = (__bf16)hv;
    float xv;
    if (toks) {
        int tok = (int)(0xFFFFFFFFu - (unsigned)(toks[b] & 0xFFFFFFFFull));
        xv = xbase[(size_t)tok * D + d];
    } else {
        xv = xbase[(size_t)b * xbstride + d];
    }
    part[dl][b] = wgen[d] * hv + wgen[768 + d] * xv;
    __syncthreads();
    if (t < 32) {
        float s = 0.f;
        #pragma unroll
        for (int i = 0; i < 8; ++i) s += part[i][t];
        pgen_part[(size_t)t * 96 + tile] = s;
    }
    __syncthreads();   // protects LDS reuse across stride-loop iterations
}

__device__ __forceinline__ void mid_tile(int tile, int t, MS& sm,
    const float* __restrict__ hnew, const __bf16* __restrict__ hbf,
    const __bf16* __restrict__ embbf,
    const float* __restrict__ enc, const int* __restrict__ ids,
    float* __restrict__ out, long outoff, long JKV,
    float* __restrict__ dpartT, float* __restrict__ logitw,
    int V, int NVB)
{
    if (tile < NLG) {
        // -------------------- attn logit tile --------------------
        const int b = tile >> 2, c = tile & 3;
        const int x0 = c * 64;
        const int l = t & 31;
        float4 hr[6];
        #pragma unroll
        for (int p = 0; p < 6; ++p)
            hr[p] = *(const float4*)(hnew + (size_t)b * D + l * 4 + p * 128);
        #pragma unroll 4
        for (int g = 0; g < 8; ++g) {
            int x = x0 + g * 8 + (t >> 5);
            const float* er = enc + ((size_t)b * XX + x) * D + l * 4;
            float acc = 0.f;
            #pragma unroll
            for (int p = 0; p < 6; ++p) {
                float4 e = *(const float4*)(er + p * 128);
                acc += e.x * hr[p].x + e.y * hr[p].y + e.z * hr[p].z + e.w * hr[p].w;
            }
            #pragma unroll
            for (int m = 1; m <= 16; m <<= 1) acc += __shfl_xor(acc, m);
            if (l == 0) {
                int id = ids[b * XX + x];
                logitw[b * XX + x] = (id == 0) ? -1e9f : acc;
            }
        }
    } else {
        // -------------------- vocab MFMA tile --------------------
        const int vb = tile - NLG;
        if (t < 32) sm.dsum[t] = 0.f;
        __syncthreads();

        const int lane = t & 63, w = t >> 6;
        const int col = lane & 15;
        const int kq  = (lane >> 4) * 8;
        int vrow = vb * 64 + w * 16 + col;
        const bool ok = vrow < V;
        const int vl = ok ? vrow : V - 1;
        const __bf16* bp  = embbf + (size_t)vl * D + kq;
        const __bf16* ap0 = hbf + (size_t)col * D + kq;
        const __bf16* ap1 = hbf + (size_t)(col + 16) * D + kq;

        f32x4 c0 = {0.f, 0.f, 0.f, 0.f};
        f32x4 c1 = {0.f, 0.f, 0.f, 0.f};
        #pragma unroll
        for (int hh = 0; hh < 2; ++hh) {
            bf16x8 bv[12];
            #pragma unroll
            for (int i = 0; i < 12; ++i)
                bv[i] = *(const bf16x8*)(bp + hh * 384 + i * 32);
            #pragma unroll
            for (int i = 0; i < 12; ++i) {
                bf16x8 a0 = *(const bf16x8*)(ap0 + hh * 384 + i * 32);
                bf16x8 a1 = *(const bf16x8*)(ap1 + hh * 384 + i * 32);
                c0 = __builtin_amdgcn_mfma_f32_16x16x32_bf16(a0, bv[i], c0, 0, 0, 0);
                c1 = __builtin_amdgcn_mfma_f32_16x16x32_bf16(a1, bv[i], c1, 0, 0, 0);
            }
        }
        const int vloc = w * 16 + col;
        #pragma unroll
        for (int r = 0; r < 4; ++r) {
            int b0 = (lane >> 4) * 4 + r;
            float e0 = ok ? __expf(c0[r]) : 0.f;
            float e1 = ok ? __expf(c1[r]) : 0.f;
            sm.sh[vloc][b0]      = e0;
            sm.sh[vloc][b0 + 16] = e1;
            #pragma unroll
            for (int m = 1; m <= 8; m <<= 1) {
                e0 += __shfl_xor(e0, m);
                e1 += __shfl_xor(e1, m);
            }
            if (col == 0) {
                atomicAdd(&sm.dsum[b0], e0);
                atomicAdd(&sm.dsum[b0 + 16], e1);
            }
        }
        __syncthreads();
        if (t < 32) dpartT[(size_t)t * 512 + vb] = sm.dsum[t];
        const int vg = vb * 64 + lane;
        if (vg < V) {
            #pragma unroll
            for (int i = 0; i < 8; ++i) {
                int bb2 = w * 8 + i;
                out[(size_t)bb2 * JKV + outoff + vg] = sm.sh[lane][bb2];
            }
        }
    }
}

__device__ __forceinline__ void fin_tile(int tile, int t, FS& s,
    float* __restrict__ out, long outoff, long JKV,
    const float* __restrict__ dpartT, int npart,
    const float* __restrict__ logitw, const float* __restrict__ penc,
    const float* __restrict__ pgen_part, const float* __restrict__ bgen,
    const int* __restrict__ ids,
    unsigned long long* __restrict__ argz, int V)
{
    const int b = tile >> 3;
    const int c = tile & 7;
    const int v0 = c * CH;

    // 1. denominator
    float sum = 0.f;
    for (int i = t; i < npart; i += 256) sum += dpartT[(size_t)b * 512 + i];
    s.red[t] = sum;
    __syncthreads();
    for (int st = 128; st > 0; st >>= 1) {
        if (t < st) s.red[t] += s.red[t + st];
        __syncthreads();
    }
    const float rd = 1.0f / s.red[0];
    __syncthreads();

    // 2. attention softmax (redundant per tile; 256 elems — trivial)
    float l = logitw[b * XX + t];
    s.red[t] = l;
    __syncthreads();
    for (int st = 128; st > 0; st >>= 1) {
        if (t < st) s.red[t] = fmaxf(s.red[t], s.red[t + st]);
        __syncthreads();
    }
    float mx = s.red[0];
    __syncthreads();
    float e = expf(l - mx);
    s.red[t] = e;
    __syncthreads();
    for (int st = 128; st > 0; st >>= 1) {
        if (t < st) s.red[t] += s.red[t + st];
        __syncthreads();
    }
    float awv = e / s.red[0];
    s.aw[t] = awv;
    __syncthreads();

    // 3. p_gen
    float pv = awv * penc[b * XX + t] + ((t < 96) ? pgen_part[(size_t)b * 96 + t] : 0.f);
    s.red[t] = pv;
    __syncthreads();
    for (int st = 128; st > 0; st >>= 1) {
        if (t < st) s.red[t] += s.red[t + st];
        __syncthreads();
    }
    const float pg = 1.0f / (1.0f + expf(-(s.red[0] + bgen[0])));
    const float og = 1.0f - pg;

    // 4. scatter p_ctx chunk
    for (int i = t; i < CH; i += 256) s.pctx[i] = 0.f;
    __syncthreads();
    {
        int id = ids[b * XX + t];
        int rel = id - v0;
        if ((unsigned)rel < (unsigned)CH) atomicAdd(&s.pctx[rel], s.aw[t]);
    }
    __syncthreads();

    // 5. normalize + argmax
    unsigned long long pk = 0ULL;
    const int vend = (v0 + CH < V) ? CH : (V - v0);
    #pragma unroll
    for (int i = 0; i < 15; ++i) {
        int v = t + 256 * i;
        if (v < vend) {
            int vg = v0 + v;
            size_t o = (size_t)b * JKV + outoff + vg;
            float ev = out[o];
            float ps = pg * ev * rd + og * s.pctx[v];
            out[o] = ps;
            unsigned long long k2 = ((unsigned long long)__float_as_uint(ps) << 32)
                                  | (unsigned long long)(0xFFFFFFFFu - (unsigned)vg);
            if (k2 > pk) pk = k2;
        }
    }
    #pragma unroll
    for (int m = 1; m < 64; m <<= 1) {
        unsigned long long o2 = __shfl_xor(pk, m);
        if (o2 > pk) pk = o2;
    }
    if ((t & 63) == 0) s.wmax[t >> 6] = pk;
    __syncthreads();
    if (t == 0) {
        unsigned long long m0 = s.wmax[0];
        #pragma unroll
        for (int i2 = 1; i2 < 4; ++i2) if (s.wmax[i2] > m0) m0 = s.wmax[i2];
        atomicMax(&argz[b], m0);
    }
    __syncthreads();   // protects LDS reuse across stride-loop iterations
}

// ---------------------------------------------------------------------------
// persistent cooperative mega-kernel: init + 32 steps x 4 phases, grid.sync
// between phases. Replaces 130 dispatches with 1.
// ---------------------------------------------------------------------------
struct Prm {
    const float *dec, *hid, *enc, *emb, *wih, *whh, *bih, *bhh, *wgen, *bgen;
    const int *ids;
    float *out;
    unsigned long long *argpack;
    float *gT, *dpartT, *logitw, *penc, *pgen_part, *h0, *h1;
    __bf16 *hbf, *embbf;
    long JKV; int V, NVB, J, K;
};

__global__ __launch_bounds__(256, 3) void k_mega(Prm p)
{
    __shared__ SMU sm;
    cg::grid_group gg = cg::this_grid();
    const int t = threadIdx.x;
    const int bid = blockIdx.x;
    const int NB = gridDim.x;

    // ---- one-time init: emb->bf16, penc
    {
        const int n8 = p.V * D / 8;
        for (int i = bid * 256 + t; i < n8; i += NB * 256)
            cvt_item(p.emb, p.embbf, i);
        for (int tile = bid; tile < 128; tile += NB)
            penc_tile(tile, t, p.enc, p.wgen, p.penc);
    }

    int step = 0;
    for (int j = 0; j < p.J; ++j) {
        for (int kk = 0; kk < p.K; ++kk, ++step) {
            const int cur = step & 1;
            float* hout = cur ? p.h1 : p.h0;
            const float* hin = (step == 0) ? p.hid : (cur ? p.h0 : p.h1);
            const float* xbase;
            long xbs;
            const unsigned long long* toks;
            if (kk == 0) {
                xbase = p.dec + (size_t)j * D;
                xbs = (long)p.J * D;
                toks = nullptr;
            } else {
                xbase = p.emb;
                xbs = D;
                toks = p.argpack + (1 - cur) * 32;
            }
            unsigned long long* argz = p.argpack + cur * 32;
            const long outoff = (long)(j * p.K + kk) * p.V;

            gg.sync();                       // prev fin / init visible
            set_tokl(t, sm.g.tokl, toks);
            for (int tile = bid; tile < 576; tile += NB)
                gates_tile(tile, t, sm.g.vec, sm.g.tokl, toks != nullptr,
                           xbase, xbs, hin, p.wih, p.whh, p.gT);
            gg.sync();                       // gT complete
            for (int tile = bid; tile < 96; tile += NB)
                comb_tile(tile, t, sm.c.part, p.gT, p.bih, p.bhh, hin,
                          xbase, xbs, toks, p.wgen, hout, p.hbf,
                          p.pgen_part, argz);
            gg.sync();                       // h/hbf/pgen_part complete
            for (int tile = bid; tile < NLG + p.NVB; tile += NB)
                mid_tile(tile, t, sm.m, hout, p.hbf, p.embbf, p.enc, p.ids,
                         p.out, outoff, p.JKV, p.dpartT, p.logitw, p.V, p.NVB);
            gg.sync();                       // exp/dpartT/logitw complete
            for (int tile = bid; tile < 256; tile += NB)
                fin_tile(tile, t, sm.f, p.out, outoff, p.JKV, p.dpartT, p.NVB,
                         p.logitw, p.penc, p.pgen_part, p.bgen, p.ids,
                         argz, p.V);
        }
    }
}

// ---------------------------------------------------------------------------
// fallback kernels (identical math; used if cooperative launch unavailable)
// ---------------------------------------------------------------------------
__global__ __launch_bounds__(256) void k_cvt(const float* __restrict__ src,
                                             __bf16* __restrict__ dst, int n8)
{
    int i = blockIdx.x * 256 + threadIdx.x;
    if (i < n8) cvt_item(src, dst, i);
}

__global__ __launch_bounds__(256) void k_penc(
    const float* __restrict__ enc, const float* __restrict__ wgen,
    float* __restrict__ penc)
{
    penc_tile(blockIdx.x, threadIdx.x, enc, wgen, penc);
}

__global__ __launch_bounds__(256) void k_gates(
    const float* __restrict__ xbase, long xbstride,
    const unsigned long long* __restrict__ toks,
    const float* __restrict__ hin,
    const float* __restrict__ wih, const float* __restrict__ whh,
    float* __restrict__ gT)
{
    __shared__ GS s;
    set_tokl(threadIdx.x, s.tokl, toks);
    gates_tile(blockIdx.x, threadIdx.x, s.vec, s.tokl, toks != nullptr,
               xbase, xbstride, hin, wih, whh, gT);
}

__global__ __launch_bounds__(256) void k_comb(
    const float* __restrict__ gT,
    const float* __restrict__ bih, const float* __restrict__ bhh,
    const float* __restrict__ hin,
    const float* __restrict__ xbase, long xbstride,
    const unsigned long long* __restrict__ toks,
    const float* __restrict__ wgen,
    float* __restrict__ hout, __bf16* __restrict__ hbf,
    float* __restrict__ pgen_part,
    unsigned long long* __restrict__ argz)
{
    __shared__ CS s;
    comb_tile(blockIdx.x, threadIdx.x, s.part, gT, bih, bhh, hin,
              xbase, xbstride, toks, wgen, hout, hbf, pgen_part, argz);
}

__global__ __launch_bounds__(256) void k_mid(
    const float* __restrict__ hnew, const __bf16* __restrict__ hbf,
    const __bf16* __restrict__ embbf,
    const float* __restrict__ enc, const int* __restrict__ ids,
    float* __restrict__ out, long outoff, long JKV,
    float* __restrict__ dpartT, float* __restrict__ logitw,
    int V, int NVB)
{
    __shared__ MS s;
    mid_tile(blockIdx.x, threadIdx.x, s, hnew, hbf, embbf, enc, ids,
             out, outoff, JKV, dpartT, logitw, V, NVB);
}

__global__ __launch_bounds__(256) void k_fin(
    float* __restrict__ out, long outoff, long JKV,
    const float* __restrict__ dpartT, int npart,
    const float* __restrict__ logitw, const float* __restrict__ penc,
    const float* __restrict__ pgen_part, const float* __restrict__ bgen,
    const int* __restrict__ ids,
    unsigned long long* __restrict__ argz, int V)
{
    __shared__ FS s;
    fin_tile(blockIdx.x, threadIdx.x, s, out, outoff, JKV, dpartT, npart,
             logitw, penc, pgen_part, bgen, ids, argz, V);
}

// ---------------------------------------------------------------------------
extern "C" void kernel_launch(void* const* d_in, const int* in_sizes, int n_in,
                              void* d_out, int out_size, void* d_ws, size_t ws_size,
                              hipStream_t stream)
{
    const float* dec  = (const float*)d_in[0];
    const float* hid  = (const float*)d_in[1];
    const float* enc  = (const float*)d_in[2];
    const int*   ids  = (const int*)d_in[3];
    const float* emb  = (const float*)d_in[5];
    const float* wih  = (const float*)d_in[6];
    const float* whh  = (const float*)d_in[7];
    const float* bih  = (const float*)d_in[8];
    const float* bhh  = (const float*)d_in[9];
    const float* wgen = (const float*)d_in[10];
    const float* bgen = (const float*)d_in[11];
    float* out = (float*)d_out;

    const int B = 32;
    const int J = in_sizes[0] / (B * D);           // 4
    const int V = in_sizes[5] / D;                 // 30522
    const int K = out_size / (B * J * V);          // 8
    const long JKV = (long)J * K * V;
    const int NVB = (V + 63) / 64;                 // 477

    // workspace carve
    char* w = (char*)d_ws;
    unsigned long long* argpack = (unsigned long long*)w; w += 1024; // 2 x 32
    float* gT        = (float*)w;  w += (size_t)4608 * 32 * 4;
    float* dpartT    = (float*)w;  w += (size_t)32 * 512 * 4;
    float* logitw    = (float*)w;  w += (size_t)B * XX * 4;
    float* penc      = (float*)w;  w += (size_t)B * XX * 4;
    float* pgen_part = (float*)w;  w += (size_t)B * 96 * 4;
    float* h0        = (float*)w;  w += (size_t)B * D * 4;
    float* h1        = (float*)w;  w += (size_t)B * D * 4;
    __bf16* hbf      = (__bf16*)w; w += (size_t)B * D * 2;
    __bf16* embbf    = (__bf16*)w; w += (size_t)V * D * 2;

    Prm prm;
    prm.dec = dec; prm.hid = hid; prm.enc = enc; prm.emb = emb;
    prm.wih = wih; prm.whh = whh; prm.bih = bih; prm.bhh = bhh;
    prm.wgen = wgen; prm.bgen = bgen; prm.ids = ids; prm.out = out;
    prm.argpack = argpack; prm.gT = gT; prm.dpartT = dpartT;
    prm.logitw = logitw; prm.penc = penc; prm.pgen_part = pgen_part;
    prm.h0 = h0; prm.h1 = h1; prm.hbf = hbf; prm.embbf = embbf;
    prm.JKV = JKV; prm.V = V; prm.NVB = NVB; prm.J = J; prm.K = K;

    // ---- preferred path: one persistent cooperative dispatch
    bool coop = false;
    {
        void* args[] = { (void*)&prm };
        if (hipLaunchCooperativeKernel((const void*)k_mega, dim3(608), dim3(256),
                                       args, 0, stream) == hipSuccess)
            coop = true;
        else if (hipLaunchCooperativeKernel((const void*)k_mega, dim3(512), dim3(256),
                                            args, 0, stream) == hipSuccess)
            coop = true;
        else if (hipLaunchCooperativeKernel((const void*)k_mega, dim3(256), dim3(256),
                                            args, 0, stream) == hipSuccess)
            coop = true;
    }
    if (coop) return;

    // ---- fallback: proven 130-dispatch path
    const int n8 = V * D / 8;
    k_cvt<<<dim3((n8 + 255) / 256), dim3(256), 0, stream>>>(emb, embbf, n8);
    k_penc<<<dim3(128), dim3(256), 0, stream>>>(enc, wgen, penc);

    int step = 0;
    for (int j = 0; j < J; ++j) {
        for (int kk = 0; kk < K; ++kk) {
            const int cur = step & 1;
            float* hout = (cur == 0) ? h0 : h1;
            const float* hin = (step == 0) ? hid : ((((step - 1) & 1) == 0) ? h0 : h1);
            const float* xbase;
            long xbs;
            const unsigned long long* toks;
            if (kk == 0) {
                xbase = dec + (size_t)j * D;
                xbs = (long)J * D;
                toks = nullptr;
            } else {
                xbase = emb;
                xbs = D;
                toks = argpack + ((step - 1) & 1) * 32;
            }
            unsigned long long* argz = argpack + cur * 32;
            const long outoff = (long)(j * K + kk) * V;

            k_gates<<<dim3(576), dim3(256), 0, stream>>>(
                xbase, xbs, toks, hin, wih, whh, gT);
            k_comb<<<dim3(96), dim3(256), 0, stream>>>(
                gT, bih, bhh, hin, xbase, xbs, toks, wgen, hout, hbf,
                pgen_part, argz);
            k_mid<<<dim3(NVB + NLG), dim3(256), 0, stream>>>(
                hout, hbf, embbf, enc, ids, out, outoff, JKV,
                dpartT, logitw, V, NVB);
            k_fin<<<dim3(256), dim3(256), 0, stream>>>(
                out, outoff, JKV, dpartT, NVB, logitw, penc, pgen_part,
                bgen, ids, argz, V);
            ++step;
        }
    }
}

// Round 3
// 4956.047 us; speedup vs baseline: 2.1599x; 2.1599x over previous
//
#include <hip/hip_runtime.h>
#include <hip/hip_bf16.h>

#define D 768
#define XX 256

typedef __bf16 bf16x8 __attribute__((ext_vector_type(8)));
typedef float  f32x4  __attribute__((ext_vector_type(4)));
typedef unsigned long long ull;

// ---------------------------------------------------------------------------
// K0: one-time: emb fp32 -> bf16, zero the 64 step-counters
// ---------------------------------------------------------------------------
__global__ __launch_bounds__(256) void k_cvt(const float* __restrict__ src,
                                             __bf16* __restrict__ dst, int n8,
                                             unsigned* __restrict__ cnt)
{
    int i = blockIdx.x * 256 + threadIdx.x;
    if (blockIdx.x == 0 && threadIdx.x < 64) cnt[threadIdx.x] = 0u;
    if (i < n8) {
        float4 f0 = *(const float4*)(src + (size_t)i * 8);
        float4 f1 = *(const float4*)(src + (size_t)i * 8 + 4);
        bf16x8 o;
        o[0] = (__bf16)f0.x; o[1] = (__bf16)f0.y; o[2] = (__bf16)f0.z; o[3] = (__bf16)f0.w;
        o[4] = (__bf16)f1.x; o[5] = (__bf16)f1.y; o[6] = (__bf16)f1.z; o[7] = (__bf16)f1.w;
        *(bf16x8*)(dst + (size_t)i * 8) = o;
    }
}

// ---------------------------------------------------------------------------
// K0b: one-time: penc[b][x] = wgen[1536:2304] . enc[b,x,:]
// ---------------------------------------------------------------------------
__global__ __launch_bounds__(256) void k_penc(
    const float* __restrict__ enc, const float* __restrict__ wgen,
    float* __restrict__ penc)
{
    const int t = threadIdx.x;
    const int b = blockIdx.x >> 2, c = blockIdx.x & 3;
    const int x0 = c * 64;
    const int l = t & 31;
    float4 wr[6];
    #pragma unroll
    for (int p = 0; p < 6; ++p)
        wr[p] = *(const float4*)(wgen + 1536 + l * 4 + p * 128);
    for (int g = 0; g < 8; ++g) {
        int x = x0 + g * 8 + (t >> 5);
        const float* er = enc + ((size_t)b * XX + x) * D + l * 4;
        float acc = 0.f;
        #pragma unroll
        for (int p = 0; p < 6; ++p) {
            float4 e = *(const float4*)(er + p * 128);
            acc += e.x * wr[p].x + e.y * wr[p].y + e.z * wr[p].z + e.w * wr[p].w;
        }
        #pragma unroll
        for (int m = 1; m <= 16; m <<= 1) acc += __shfl_xor(acc, m);
        if (l == 0) penc[b * XX + x] = acc;
    }
}

// ---------------------------------------------------------------------------
// K1: fused GRU (gates GEMM + combine). grid 96 x 256.
// thread (b = t&31, rl = t>>5) owns d = bid*8+rl: computes all 6 gate dots.
// ---------------------------------------------------------------------------
__global__ __launch_bounds__(256) void k_gru(
    const float* __restrict__ xbase, long xbs,
    const unsigned long long* __restrict__ toks,
    const float* __restrict__ hin,
    const float* __restrict__ wih, const float* __restrict__ whh,
    const float* __restrict__ bih, const float* __restrict__ bhh,
    const float* __restrict__ wgen,
    float* __restrict__ hout, __bf16* __restrict__ hbf,
    float* __restrict__ pgen_part)
{
    __shared__ __align__(16) float xs[32][132];
    __shared__ __align__(16) float hs[32][132];
    __shared__ int tokl[32];
    __shared__ float part[8][32];
    const int t = threadIdx.x, bid = blockIdx.x;
    const int b = t & 31, rl = t >> 5;
    const int d = bid * 8 + rl;
    if (t < 32)
        tokl[t] = toks ? (int)(0xFFFFFFFFu - (unsigned)(toks[t] & 0xFFFFFFFFull)) : 0;

    const float* w0 = wih + (size_t)d * D;
    const float* w1 = wih + (size_t)(768 + d) * D;
    const float* w2 = wih + (size_t)(1536 + d) * D;
    const float* w3 = whh + (size_t)d * D;
    const float* w4 = whh + (size_t)(768 + d) * D;
    const float* w5 = whh + (size_t)(1536 + d) * D;

    float aIR = 0.f, aIZ = 0.f, aIN = 0.f, aHR = 0.f, aHZ = 0.f, aHN = 0.f;
    for (int c = 0; c < 6; ++c) {
        const int kc = c * 128;
        __syncthreads();
        for (int p = 0; p < 4; ++p) {
            int fid = t + 256 * p;
            int bb = fid >> 5, k4 = (fid & 31) * 4;
            const float* sx = toks ? (xbase + (size_t)tokl[bb] * D)
                                   : (xbase + (size_t)bb * xbs);
            *(float4*)&xs[bb][k4] = *(const float4*)(sx + kc + k4);
            *(float4*)&hs[bb][k4] = *(const float4*)(hin + (size_t)bb * D + kc + k4);
        }
        __syncthreads();
        #pragma unroll 8
        for (int k4 = 0; k4 < 128; k4 += 4) {
            float4 xv = *(const float4*)&xs[b][k4];
            float4 hv = *(const float4*)&hs[b][k4];
            float4 wv;
            wv = *(const float4*)(w0 + kc + k4);
            aIR += wv.x * xv.x + wv.y * xv.y + wv.z * xv.z + wv.w * xv.w;
            wv = *(const float4*)(w1 + kc + k4);
            aIZ += wv.x * xv.x + wv.y * xv.y + wv.z * xv.z + wv.w * xv.w;
            wv = *(const float4*)(w2 + kc + k4);
            aIN += wv.x * xv.x + wv.y * xv.y + wv.z * xv.z + wv.w * xv.w;
            wv = *(const float4*)(w3 + kc + k4);
            aHR += wv.x * hv.x + wv.y * hv.y + wv.z * hv.z + wv.w * hv.w;
            wv = *(const float4*)(w4 + kc + k4);
            aHZ += wv.x * hv.x + wv.y * hv.y + wv.z * hv.z + wv.w * hv.w;
            wv = *(const float4*)(w5 + kc + k4);
            aHN += wv.x * hv.x + wv.y * hv.y + wv.z * hv.z + wv.w * hv.w;
        }
    }
    float ir = aIR + bih[d];
    float iz = aIZ + bih[768 + d];
    float in_ = aIN + bih[1536 + d];
    float hr = aHR + bhh[d];
    float hz = aHZ + bhh[768 + d];
    float hn = aHN + bhh[1536 + d];
    float r = 1.0f / (1.0f + expf(-(ir + hr)));
    float z = 1.0f / (1.0f + expf(-(iz + hz)));
    float n = tanhf(in_ + r * hn);
    float hold = hin[(size_t)b * D + d];
    float hv2 = (1.0f - z) * n + z * hold;
    hout[(size_t)b * D + d] = hv2;
    hbf[(size_t)b * D + d] = (__bf16)hv2;
    float xv2;
    if (toks) xv2 = xbase[(size_t)tokl[b] * D + d];
    else      xv2 = xbase[(size_t)b * xbs + d];
    part[rl][b] = wgen[d] * hv2 + wgen[768 + d] * xv2;
    __syncthreads();
    if (t < 32) {
        float s = 0.f;
        #pragma unroll
        for (int i = 0; i < 8; ++i) s += part[i][t];
        pgen_part[(size_t)t * 96 + bid] = s;
    }
}

// ---------------------------------------------------------------------------
// K2: fused mid+fin. grid EXACTLY 256 blocks (<= 1/CU => guaranteed resident,
// so the semaphore barrier cannot deadlock).
// Pre-barrier:  attn-logit slice (b=bid>>3, 32 x's) + 1-2 vocab MFMA tiles
//               (tiles bid and bid+256), exp kept in LDS, denom partial out.
// Barrier:      threadfence + atomicAdd(doneA) + spin to gridDim arrivals.
// Post-barrier: per-b (8-lane groups) denom/softmax/pgen, pctx scatter into
//               LDS, normalize from LDS, single final out write, block argmax
//               -> wmaxArr; blocks 0..31 reduce wmaxArr -> argz.
// ---------------------------------------------------------------------------
__global__ __launch_bounds__(256) void k_midfin(
    const float* __restrict__ hnew, const __bf16* __restrict__ hbf,
    const __bf16* __restrict__ embbf,
    const float* __restrict__ enc, const int* __restrict__ ids,
    const float* __restrict__ penc, const float* __restrict__ pgen_part,
    const float* __restrict__ bgen,
    float* __restrict__ out, long outoff, long JKV,
    float* __restrict__ dpartT, float* __restrict__ logitw,
    ull* __restrict__ wmaxArr, ull* __restrict__ argz,
    unsigned* __restrict__ doneA, unsigned* __restrict__ doneB,
    int V, int NT)
{
    __shared__ float shEx[128][33];
    __shared__ float shP[128][33];
    __shared__ float dsum[32];
    __shared__ float pgL[32], rdL[32], ogL[32];
    __shared__ ull redq[256];
    const int t = threadIdx.x, bid = blockIdx.x;
    const int NBLK = gridDim.x;          // 256

    // ---------------- phase A1: attn logit slice ----------------
    {
        const int b = bid >> 3, x0 = (bid & 7) * 32;
        const int l = t & 31;
        float4 hr[6];
        #pragma unroll
        for (int p = 0; p < 6; ++p)
            hr[p] = *(const float4*)(hnew + (size_t)b * D + l * 4 + p * 128);
        for (int g = 0; g < 4; ++g) {
            int x = x0 + g * 8 + (t >> 5);
            const float* er = enc + ((size_t)b * XX + x) * D + l * 4;
            float acc = 0.f;
            #pragma unroll
            for (int p = 0; p < 6; ++p) {
                float4 e = *(const float4*)(er + p * 128);
                acc += e.x * hr[p].x + e.y * hr[p].y + e.z * hr[p].z + e.w * hr[p].w;
            }
            #pragma unroll
            for (int m = 1; m <= 16; m <<= 1) acc += __shfl_xor(acc, m);
            if (l == 0) {
                int id = ids[b * XX + x];
                logitw[b * XX + x] = (id == 0) ? -1e9f : acc;
            }
        }
    }

    // ---------------- phase A2: vocab MFMA tiles ----------------
    if (t < 32) dsum[t] = 0.f;
    for (int i = t; i < 128 * 33; i += 256) ((float*)shP)[i] = 0.f;
    __syncthreads();

    const int lane = t & 63, wv_ = t >> 6;
    const int col = lane & 15;
    const int kq  = (lane >> 4) * 8;
    const __bf16* ap0 = hbf + (size_t)col * D + kq;
    const __bf16* ap1 = hbf + (size_t)(col + 16) * D + kq;

    #pragma unroll
    for (int s2 = 0; s2 < 2; ++s2) {
        const int vt = bid + s2 * NBLK;
        if (vt < NT) {
            const int vrow = vt * 64 + wv_ * 16 + col;
            const bool ok = vrow < V;
            const __bf16* bp = embbf + (size_t)(ok ? vrow : V - 1) * D + kq;
            f32x4 c0 = {0.f, 0.f, 0.f, 0.f};
            f32x4 c1 = {0.f, 0.f, 0.f, 0.f};
            #pragma unroll
            for (int hh = 0; hh < 2; ++hh) {
                bf16x8 bv[12];
                #pragma unroll
                for (int i = 0; i < 12; ++i)
                    bv[i] = *(const bf16x8*)(bp + hh * 384 + i * 32);
                #pragma unroll
                for (int i = 0; i < 12; ++i) {
                    bf16x8 a0 = *(const bf16x8*)(ap0 + hh * 384 + i * 32);
                    bf16x8 a1 = *(const bf16x8*)(ap1 + hh * 384 + i * 32);
                    c0 = __builtin_amdgcn_mfma_f32_16x16x32_bf16(a0, bv[i], c0, 0, 0, 0);
                    c1 = __builtin_amdgcn_mfma_f32_16x16x32_bf16(a1, bv[i], c1, 0, 0, 0);
                }
            }
            const int vloc = s2 * 64 + wv_ * 16 + col;
            #pragma unroll
            for (int r = 0; r < 4; ++r) {
                int b0 = (lane >> 4) * 4 + r;
                float e0 = ok ? __expf(c0[r]) : 0.f;
                float e1 = ok ? __expf(c1[r]) : 0.f;
                shEx[vloc][b0]      = e0;
                shEx[vloc][b0 + 16] = e1;
                #pragma unroll
                for (int m = 1; m <= 8; m <<= 1) {
                    e0 += __shfl_xor(e0, m);
                    e1 += __shfl_xor(e1, m);
                }
                if (col == 0) {
                    atomicAdd(&dsum[b0], e0);
                    atomicAdd(&dsum[b0 + 16], e1);
                }
            }
        }
    }
    __syncthreads();
    if (t < 32) dpartT[(size_t)t * 256 + bid] = dsum[t];

    // ---------------- barrier: release + arrive + spin ----------------
    __threadfence();
    __syncthreads();
    if (t == 0) {
        atomicAdd(doneA, 1u);
        while (__hip_atomic_load(doneA, __ATOMIC_RELAXED, __HIP_MEMORY_SCOPE_AGENT)
               < (unsigned)NBLK)
            __builtin_amdgcn_s_sleep(8);
        __threadfence();
    }
    __syncthreads();

    // ---------------- phase B: finalize ----------------
    const int bg = t >> 3, l8 = t & 7;   // 8 lanes per b
    // 1. denominator
    float s = 0.f;
    for (int i = l8; i < 256; i += 8) s += dpartT[(size_t)bg * 256 + i];
    s += __shfl_xor(s, 1); s += __shfl_xor(s, 2); s += __shfl_xor(s, 4);
    const float rd = 1.0f / s;
    // 2. attention softmax (32 x per lane)
    float lgv[32];
    #pragma unroll
    for (int i = 0; i < 32; ++i) lgv[i] = logitw[bg * XX + l8 * 32 + i];
    float mx = -1e30f;
    #pragma unroll
    for (int i = 0; i < 32; ++i) mx = fmaxf(mx, lgv[i]);
    mx = fmaxf(mx, __shfl_xor(mx, 1));
    mx = fmaxf(mx, __shfl_xor(mx, 2));
    mx = fmaxf(mx, __shfl_xor(mx, 4));
    float asum = 0.f;
    #pragma unroll
    for (int i = 0; i < 32; ++i) {
        float e = expf(lgv[i] - mx);
        lgv[i] = e;
        asum += e;
    }
    asum += __shfl_xor(asum, 1); asum += __shfl_xor(asum, 2); asum += __shfl_xor(asum, 4);
    const float ainv = 1.0f / asum;
    // 3. p_gen
    float pv = 0.f;
    #pragma unroll
    for (int i = 0; i < 32; ++i)
        pv += lgv[i] * ainv * penc[bg * XX + l8 * 32 + i];
    for (int i = l8; i < 96; i += 8) pv += pgen_part[(size_t)bg * 96 + i];
    pv += __shfl_xor(pv, 1); pv += __shfl_xor(pv, 2); pv += __shfl_xor(pv, 4);
    const float pg = 1.0f / (1.0f + expf(-(pv + bgen[0])));
    if (l8 == 0) { pgL[bg] = pg; rdL[bg] = rd; ogL[bg] = 1.0f - pg; }
    // 4. pctx scatter into LDS
    const int base0 = bid * 64;
    const int base1 = (bid + NBLK) * 64;
    const bool has1 = (bid + NBLK) < NT;
    #pragma unroll
    for (int i = 0; i < 32; ++i) {
        int x = l8 * 32 + i;
        int id = ids[bg * XX + x];
        float awv = lgv[i] * ainv;
        int r0 = id - base0;
        if ((unsigned)r0 < 64u) atomicAdd(&shP[r0][bg], awv);
        if (has1) {
            int r1 = id - base1;
            if ((unsigned)r1 < 64u) atomicAdd(&shP[64 + r1][bg], awv);
        }
    }
    __syncthreads();
    // 5. normalize + single final store + argmax
    ull pk[8];
    #pragma unroll
    for (int i = 0; i < 8; ++i) pk[i] = 0ULL;
    {
        int vg = base0 + lane;           // tile 0: always < V (bid < 256)
        #pragma unroll
        for (int i = 0; i < 8; ++i) {
            int bb = wv_ * 8 + i;
            float ps = pgL[bb] * rdL[bb] * shEx[lane][bb] + ogL[bb] * shP[lane][bb];
            out[(size_t)bb * JKV + outoff + vg] = ps;
            ull k2 = ((ull)__float_as_uint(ps) << 32)
                   | (ull)(0xFFFFFFFFu - (unsigned)vg);
            if (k2 > pk[i]) pk[i] = k2;
        }
    }
    if (has1) {
        int vg = base1 + lane;
        if (vg < V) {
            #pragma unroll
            for (int i = 0; i < 8; ++i) {
                int bb = wv_ * 8 + i;
                float ps = pgL[bb] * rdL[bb] * shEx[64 + lane][bb] + ogL[bb] * shP[64 + lane][bb];
                out[(size_t)bb * JKV + outoff + vg] = ps;
                ull k2 = ((ull)__float_as_uint(ps) << 32)
                       | (ull)(0xFFFFFFFFu - (unsigned)vg);
                if (k2 > pk[i]) pk[i] = k2;
            }
        }
    }
    #pragma unroll
    for (int i = 0; i < 8; ++i) {
        #pragma unroll
        for (int m = 1; m < 64; m <<= 1) {
            ull o2 = __shfl_xor(pk[i], m);
            if (o2 > pk[i]) pk[i] = o2;
        }
    }
    if (lane == 0) {
        #pragma unroll
        for (int i = 0; i < 8; ++i)
            wmaxArr[(size_t)bid * 32 + wv_ * 8 + i] = pk[i];
    }
    __threadfence();
    __syncthreads();
    if (t == 0) atomicAdd(doneB, 1u);

    // blocks 0..31: final argmax reduce for b = bid
    if (bid < 32) {
        if (t == 0) {
            while (__hip_atomic_load(doneB, __ATOMIC_RELAXED, __HIP_MEMORY_SCOPE_AGENT)
                   < (unsigned)NBLK)
                __builtin_amdgcn_s_sleep(8);
            __threadfence();
        }
        __syncthreads();
        redq[t] = wmaxArr[(size_t)t * 32 + bid];
        __syncthreads();
        for (int st = 128; st > 0; st >>= 1) {
            if (t < st) { if (redq[t + st] > redq[t]) redq[t] = redq[t + st]; }
            __syncthreads();
        }
        if (t == 0) argz[bid] = redq[0];
    }
}

// ---------------------------------------------------------------------------
extern "C" void kernel_launch(void* const* d_in, const int* in_sizes, int n_in,
                              void* d_out, int out_size, void* d_ws, size_t ws_size,
                              hipStream_t stream)
{
    const float* dec  = (const float*)d_in[0];
    const float* hid  = (const float*)d_in[1];
    const float* enc  = (const float*)d_in[2];
    const int*   ids  = (const int*)d_in[3];
    const float* emb  = (const float*)d_in[5];
    const float* wih  = (const float*)d_in[6];
    const float* whh  = (const float*)d_in[7];
    const float* bih  = (const float*)d_in[8];
    const float* bhh  = (const float*)d_in[9];
    const float* wgen = (const float*)d_in[10];
    const float* bgen = (const float*)d_in[11];
    float* out = (float*)d_out;

    const int B = 32;
    const int J = in_sizes[0] / (B * D);           // 4
    const int V = in_sizes[5] / D;                 // 30522
    const int K = out_size / (B * J * V);          // 8
    const long JKV = (long)J * K * V;
    const int NT = (V + 63) / 64;                  // 477 vocab tiles

    // workspace carve
    char* w = (char*)d_ws;
    ull*  argpack   = (ull*)w;      w += 1024;                      // 2 x 32
    float* dpartT    = (float*)w;   w += (size_t)32 * 256 * 4;
    float* logitw    = (float*)w;   w += (size_t)B * XX * 4;
    float* penc      = (float*)w;   w += (size_t)B * XX * 4;
    float* pgen_part = (float*)w;   w += (size_t)B * 96 * 4;
    float* h0        = (float*)w;   w += (size_t)B * D * 4;
    float* h1        = (float*)w;   w += (size_t)B * D * 4;
    ull*  wmaxArr   = (ull*)w;      w += (size_t)256 * 32 * 8;
    unsigned* cnt    = (unsigned*)w; w += 64 * 4;                   // doneA[32], doneB[32]
    __bf16* hbf      = (__bf16*)w;  w += (size_t)B * D * 2;
    __bf16* embbf    = (__bf16*)w;  w += (size_t)V * D * 2;

    const int n8 = V * D / 8;
    k_cvt<<<dim3((n8 + 255) / 256), dim3(256), 0, stream>>>(emb, embbf, n8, cnt);
    k_penc<<<dim3(128), dim3(256), 0, stream>>>(enc, wgen, penc);

    int step = 0;
    for (int j = 0; j < J; ++j) {
        for (int kk = 0; kk < K; ++kk, ++step) {
            const int cur = step & 1;
            float* hout = (cur == 0) ? h0 : h1;
            const float* hin = (step == 0) ? hid : ((((step - 1) & 1) == 0) ? h0 : h1);
            const float* xbase;
            long xbs;
            const unsigned long long* toks;
            if (kk == 0) {
                xbase = dec + (size_t)j * D;
                xbs = (long)J * D;
                toks = nullptr;
            } else {
                xbase = emb;
                xbs = D;
                toks = argpack + ((step - 1) & 1) * 32;
            }
            ull* argz = argpack + cur * 32;
            const long outoff = (long)(j * K + kk) * V;

            k_gru<<<dim3(96), dim3(256), 0, stream>>>(
                xbase, xbs, toks, hin, wih, whh, bih, bhh, wgen,
                hout, hbf, pgen_part);
            k_midfin<<<dim3(256), dim3(256), 0, stream>>>(
                hout, hbf, embbf, enc, ids, penc, pgen_part, bgen,
                out, outoff, JKV, dpartT, logitw, wmaxArr, argz,
                cnt + step, cnt + 32 + step, V, NT);
        }
    }
}

// Round 4
// 2291.429 us; speedup vs baseline: 4.6716x; 2.1629x over previous
//
#include <hip/hip_runtime.h>
#include <hip/hip_bf16.h>

#define D 768
#define BB 32
#define XX 256
#define CH 3816   // vocab chunk per k_fin block (8 chunks cover 30522)
#define NLG 128   // attn logit blocks (scheduled first in k_mid)

typedef __bf16 bf16x8 __attribute__((ext_vector_type(8)));
typedef float  f32x4  __attribute__((ext_vector_type(4)));

// ---------------------------------------------------------------------------
// K0: one-time: emb fp32 -> bf16
// ---------------------------------------------------------------------------
__global__ __launch_bounds__(256) void k_cvt(const float* __restrict__ src,
                                             __bf16* __restrict__ dst, int n8)
{
    int i = blockIdx.x * 256 + threadIdx.x;
    if (i < n8) {
        float4 f0 = *(const float4*)(src + (size_t)i * 8);
        float4 f1 = *(const float4*)(src + (size_t)i * 8 + 4);
        bf16x8 o;
        o[0] = (__bf16)f0.x; o[1] = (__bf16)f0.y; o[2] = (__bf16)f0.z; o[3] = (__bf16)f0.w;
        o[4] = (__bf16)f1.x; o[5] = (__bf16)f1.y; o[6] = (__bf16)f1.z; o[7] = (__bf16)f1.w;
        *(bf16x8*)(dst + (size_t)i * 8) = o;
    }
}

// ---------------------------------------------------------------------------
// K0b: one-time: penc[b][x] = wgen[1536:2304] . enc[b,x,:]
// ---------------------------------------------------------------------------
__global__ __launch_bounds__(256) void k_penc(
    const float* __restrict__ enc, const float* __restrict__ wgen,
    float* __restrict__ penc)
{
    const int t = threadIdx.x;
    const int b = blockIdx.x >> 2, c = blockIdx.x & 3;
    const int x0 = c * 64;
    const int l = t & 31;
    float4 wr[6];
    #pragma unroll
    for (int p = 0; p < 6; ++p)
        wr[p] = *(const float4*)(wgen + 1536 + l * 4 + p * 128);
    for (int g = 0; g < 8; ++g) {
        int x = x0 + g * 8 + (t >> 5);
        const float* er = enc + ((size_t)b * XX + x) * D + l * 4;
        float acc = 0.f;
        #pragma unroll
        for (int p = 0; p < 6; ++p) {
            float4 e = *(const float4*)(er + p * 128);
            acc += e.x * wr[p].x + e.y * wr[p].y + e.z * wr[p].z + e.w * wr[p].w;
        }
        #pragma unroll
        for (int m = 1; m <= 16; m <<= 1) acc += __shfl_xor(acc, m);
        if (l == 0) penc[b * XX + x] = acc;
    }
}

// ---------------------------------------------------------------------------
// K1: GRU gates GEMM, fp32. gT[row 0..4607][b 0..31]. grid 576 x 256.
// ---------------------------------------------------------------------------
__global__ __launch_bounds__(256) void k_gates(
    const float* __restrict__ xbase, long xbstride,
    const unsigned long long* __restrict__ toks,
    const float* __restrict__ hin,
    const float* __restrict__ wih, const float* __restrict__ whh,
    float* __restrict__ gT)
{
    __shared__ __align__(16) float vec[BB][132];
    __shared__ int tokl[BB];
    const int t = threadIdx.x, bid = blockIdx.x;
    const int b = t & 31, rl = t >> 5;
    const int rglob = bid * 8 + rl;
    const bool isH = rglob >= 2304;
    const int row = isH ? rglob - 2304 : rglob;
    const float* w = (isH ? whh : wih) + (size_t)row * D;
    if (t < 32) tokl[t] = toks ? (int)(0xFFFFFFFFu - (unsigned)(toks[t] & 0xFFFFFFFFull)) : 0;

    float acc = 0.f;
    for (int c = 0; c < 6; ++c) {
        const int kc = c * 128;
        __syncthreads();
        for (int p = 0; p < 4; ++p) {
            int fid = t + 256 * p;
            int bb = fid >> 5, k4 = (fid & 31) * 4;
            const float* src;
            if (isH) src = hin + (size_t)bb * D;
            else     src = toks ? (xbase + (size_t)tokl[bb] * D)
                                : (xbase + (size_t)bb * xbstride);
            *(float4*)&vec[bb][k4] = *(const float4*)(src + kc + k4);
        }
        __syncthreads();
        #pragma unroll
        for (int k4 = 0; k4 < 128; k4 += 4) {
            float4 wv = *(const float4*)(w + kc + k4);
            float4 xv = *(const float4*)&vec[b][k4];
            acc += wv.x * xv.x + wv.y * xv.y + wv.z * xv.z + wv.w * xv.w;
        }
    }
    gT[(size_t)rglob * 32 + b] = acc;
}

// ---------------------------------------------------------------------------
// K2: GRU combine -> h (fp32 + bf16); zero argz; pgen partials. grid 96 x 256.
// ---------------------------------------------------------------------------
__global__ __launch_bounds__(256) void k_comb(
    const float* __restrict__ gT,
    const float* __restrict__ bih, const float* __restrict__ bhh,
    const float* __restrict__ hin,
    const float* __restrict__ xbase, long xbstride,
    const unsigned long long* __restrict__ toks,
    const float* __restrict__ wgen,
    float* __restrict__ hout, __bf16* __restrict__ hbf,
    float* __restrict__ pgen_part,
    unsigned long long* __restrict__ argz)
{
    __shared__ float part[8][32];
    const int t = threadIdx.x, bid = blockIdx.x;
    const int b = t & 31, dl = t >> 5;
    const int d = bid * 8 + dl;
    if (bid == 0 && t < 32) argz[t] = 0ULL;
    float ir = gT[(size_t)d * 32 + b]            + bih[d];
    float iz = gT[(size_t)(768 + d) * 32 + b]    + bih[768 + d];
    float in_ = gT[(size_t)(1536 + d) * 32 + b]  + bih[1536 + d];
    float hr = gT[(size_t)(2304 + d) * 32 + b]   + bhh[d];
    float hz = gT[(size_t)(3072 + d) * 32 + b]   + bhh[768 + d];
    float hn = gT[(size_t)(3840 + d) * 32 + b]   + bhh[1536 + d];
    float r = 1.0f / (1.0f + expf(-(ir + hr)));
    float z = 1.0f / (1.0f + expf(-(iz + hz)));
    float n = tanhf(in_ + r * hn);
    float hold = hin[(size_t)b * D + d];
    float hv = (1.0f - z) * n + z * hold;
    hout[(size_t)b * D + d] = hv;
    hbf[(size_t)b * D + d] = (__bf16)hv;
    float xv;
    if (toks) {
        int tok = (int)(0xFFFFFFFFu - (unsigned)(toks[b] & 0xFFFFFFFFull));
        xv = xbase[(size_t)tok * D + d];
    } else {
        xv = xbase[(size_t)b * xbstride + d];
    }
    part[dl][b] = wgen[d] * hv + wgen[768 + d] * xv;
    __syncthreads();
    if (t < 32) {
        float s = 0.f;
        #pragma unroll
        for (int i = 0; i < 8; ++i) s += part[i][t];
        pgen_part[(size_t)t * 96 + bid] = s;
    }
}

// ---------------------------------------------------------------------------
// K3: attn logit blocks FIRST (bid < NLG), then vocab MFMA blocks.
// Vocab path v3: embbf tile streamed via global_load_lds width=16 into a
// double-buffered, XOR-swizzled LDS tile. Each wave stages exactly the 16
// rows it consumes -> NO barriers in the stream loop; per-wave pipeline with
// counted s_waitcnt vmcnt(4). Math is bit-identical to the previous version.
// ---------------------------------------------------------------------------
struct __align__(16) MSE { float sh[64][33]; float dsum[32]; };
union  __align__(16) MSU { __bf16 buf[2][64][128]; MSE e; };

__device__ __forceinline__ void stage_chunk(
    const char* __restrict__ embb, int vb, int c, int w, int lane,
    char* lbuf, int V)
{
    // 4 insts per wave; inst g covers LDS rows 4g..4g+3 (this wave's rows)
    #pragma unroll
    for (int i = 0; i < 4; ++i) {
        const int g = w * 4 + i;
        const int row = g * 4 + (lane >> 4);
        int grow = vb * 64 + row;
        grow = (grow < V) ? grow : (V - 1);
        const int cb = ((lane & 15) << 4) ^ ((row & 7) << 4);  // inverse swizzle on src
        const char* gp = embb + (size_t)grow * 1536 + (size_t)c * 256 + cb;
        char* lp = lbuf + g * 1024;                            // wave-uniform, linear dest
        __builtin_amdgcn_global_load_lds(
            (const __attribute__((address_space(1))) unsigned int*)gp,
            (__attribute__((address_space(3))) unsigned int*)lp, 16, 0, 0);
    }
}

__global__ __launch_bounds__(256) void k_mid(
    const float* __restrict__ hnew, const __bf16* __restrict__ hbf,
    const __bf16* __restrict__ embbf,
    const float* __restrict__ enc, const int* __restrict__ ids,
    float* __restrict__ out, long outoff, long JKV,
    float* __restrict__ dpartT, float* __restrict__ logitw,
    int V, int NVB)
{
    __shared__ MSU u;
    const int t = threadIdx.x;
    const int bid = blockIdx.x;

    if (bid < NLG) {
        // -------------------- attn logit block --------------------
        const int b = bid >> 2, c = bid & 3;
        const int x0 = c * 64;
        const int l = t & 31;
        float4 hr[6];
        #pragma unroll
        for (int p = 0; p < 6; ++p)
            hr[p] = *(const float4*)(hnew + (size_t)b * D + l * 4 + p * 128);
        #pragma unroll 4
        for (int g = 0; g < 8; ++g) {
            int x = x0 + g * 8 + (t >> 5);
            const float* er = enc + ((size_t)b * XX + x) * D + l * 4;
            float acc = 0.f;
            #pragma unroll
            for (int p = 0; p < 6; ++p) {
                float4 e = *(const float4*)(er + p * 128);
                acc += e.x * hr[p].x + e.y * hr[p].y + e.z * hr[p].z + e.w * hr[p].w;
            }
            #pragma unroll
            for (int m = 1; m <= 16; m <<= 1) acc += __shfl_xor(acc, m);
            if (l == 0) {
                int id = ids[b * XX + x];
                logitw[b * XX + x] = (id == 0) ? -1e9f : acc;
            }
        }
    } else {
        // -------------------- vocab MFMA block (LDS-staged) --------------------
        const int vb = bid - NLG;          // 0..NVB-1
        const int lane = t & 63, w = t >> 6;
        const int col = lane & 15;
        const int hi = lane >> 4;          // 0..3
        const int vrow = vb * 64 + w * 16 + col;
        const bool ok = vrow < V;
        const __bf16* ap0 = hbf + (size_t)col * D + hi * 8;
        const __bf16* ap1 = hbf + (size_t)(col + 16) * D + hi * 8;
        const char* embb = (const char*)embbf;

        // prologue: stage chunk 0
        stage_chunk(embb, vb, 0, w, lane, (char*)&u.buf[0][0][0], V);

        f32x4 c0 = {0.f, 0.f, 0.f, 0.f};
        f32x4 c1 = {0.f, 0.f, 0.f, 0.f};
        const int rl = w * 16 + col;
        const int swz = (rl & 7) << 4;
        for (int c = 0; c < 6; ++c) {
            if (c < 5) {
                stage_chunk(embb, vb, c + 1, w, lane,
                            (char*)&u.buf[(c + 1) & 1][0][0], V);
                asm volatile("s_waitcnt vmcnt(4)" ::: "memory");  // chunk c resident
            } else {
                asm volatile("s_waitcnt vmcnt(0)" ::: "memory");
            }
            const char* bbuf = (const char*)&u.buf[c & 1][0][0];
            #pragma unroll
            for (int q = 0; q < 4; ++q) {
                const int cbl = q * 64 + (hi << 4);
                bf16x8 bv = *(const bf16x8*)(bbuf + rl * 256 + (cbl ^ swz));
                const int kg = c * 128 + q * 32;
                bf16x8 a0 = *(const bf16x8*)(ap0 + kg);
                bf16x8 a1 = *(const bf16x8*)(ap1 + kg);
                c0 = __builtin_amdgcn_mfma_f32_16x16x32_bf16(a0, bv, c0, 0, 0, 0);
                c1 = __builtin_amdgcn_mfma_f32_16x16x32_bf16(a1, bv, c1, 0, 0, 0);
            }
        }

        // -------------------- epilogue (union reuse: sync first) --------------------
        __syncthreads();
        if (t < 32) u.e.dsum[t] = 0.f;
        __syncthreads();
        const int vloc = w * 16 + col;
        #pragma unroll
        for (int r = 0; r < 4; ++r) {
            int b0 = hi * 4 + r;
            float e0 = ok ? __expf(c0[r]) : 0.f;
            float e1 = ok ? __expf(c1[r]) : 0.f;
            u.e.sh[vloc][b0]      = e0;
            u.e.sh[vloc][b0 + 16] = e1;
            #pragma unroll
            for (int m = 1; m <= 8; m <<= 1) {
                e0 += __shfl_xor(e0, m);
                e1 += __shfl_xor(e1, m);
            }
            if (col == 0) {
                atomicAdd(&u.e.dsum[b0], e0);
                atomicAdd(&u.e.dsum[b0 + 16], e1);
            }
        }
        __syncthreads();
        if (t < 32) dpartT[(size_t)t * 512 + vb] = u.e.dsum[t];

        // coalesced store: each wave writes 8 b-rows, 64 consecutive floats
        const int vg = vb * 64 + lane;
        if (vg < V) {
            #pragma unroll
            for (int i = 0; i < 8; ++i) {
                int bb2 = w * 8 + i;
                out[(size_t)bb2 * JKV + outoff + vg] = u.e.sh[lane][bb2];
            }
        }
    }
}

// ---------------------------------------------------------------------------
// K4: finalize (verbatim round-1).
// ---------------------------------------------------------------------------
__global__ __launch_bounds__(256) void k_fin(
    float* __restrict__ out, long outoff, long JKV,
    const float* __restrict__ dpartT, int npart,
    const float* __restrict__ logitw, const float* __restrict__ penc,
    const float* __restrict__ pgen_part, const float* __restrict__ bgen,
    const int* __restrict__ ids,
    unsigned long long* __restrict__ argz, int V)
{
    __shared__ float pctx[CH];
    __shared__ float red[256];
    __shared__ float aw[256];
    __shared__ unsigned long long wmax[4];
    const int t = threadIdx.x;
    const int b = blockIdx.x >> 3;
    const int c = blockIdx.x & 7;
    const int v0 = c * CH;

    // 1. denominator
    float s = 0.f;
    for (int i = t; i < npart; i += 256) s += dpartT[(size_t)b * 512 + i];
    red[t] = s;
    __syncthreads();
    for (int st = 128; st > 0; st >>= 1) {
        if (t < st) red[t] += red[t + st];
        __syncthreads();
    }
    const float rd = 1.0f / red[0];
    __syncthreads();

    // 2. attention softmax
    float l = logitw[b * XX + t];
    red[t] = l;
    __syncthreads();
    for (int st = 128; st > 0; st >>= 1) {
        if (t < st) red[t] = fmaxf(red[t], red[t + st]);
        __syncthreads();
    }
    float mx = red[0];
    __syncthreads();
    float e = expf(l - mx);
    red[t] = e;
    __syncthreads();
    for (int st = 128; st > 0; st >>= 1) {
        if (t < st) red[t] += red[t + st];
        __syncthreads();
    }
    float awv = e / red[0];
    aw[t] = awv;
    __syncthreads();

    // 3. p_gen
    float pv = awv * penc[b * XX + t] + ((t < 96) ? pgen_part[(size_t)b * 96 + t] : 0.f);
    red[t] = pv;
    __syncthreads();
    for (int st = 128; st > 0; st >>= 1) {
        if (t < st) red[t] += red[t + st];
        __syncthreads();
    }
    const float pg = 1.0f / (1.0f + expf(-(red[0] + bgen[0])));
    const float og = 1.0f - pg;

    // 4. scatter p_ctx chunk
    for (int i = t; i < CH; i += 256) pctx[i] = 0.f;
    __syncthreads();
    {
        int id = ids[b * XX + t];
        int rel = id - v0;
        if ((unsigned)rel < (unsigned)CH) atomicAdd(&pctx[rel], aw[t]);
    }
    __syncthreads();

    // 5. normalize + argmax
    unsigned long long pk = 0ULL;
    const int vend = (v0 + CH < V) ? CH : (V - v0);
    #pragma unroll
    for (int i = 0; i < 15; ++i) {
        int v = t + 256 * i;
        if (v < vend) {
            int vg = v0 + v;
            size_t o = (size_t)b * JKV + outoff + vg;
            float ev = out[o];
            float ps = pg * ev * rd + og * pctx[v];
            out[o] = ps;
            unsigned long long k2 = ((unsigned long long)__float_as_uint(ps) << 32)
                                  | (unsigned long long)(0xFFFFFFFFu - (unsigned)vg);
            if (k2 > pk) pk = k2;
        }
    }
    #pragma unroll
    for (int m = 1; m < 64; m <<= 1) {
        unsigned long long o2 = __shfl_xor(pk, m);
        if (o2 > pk) pk = o2;
    }
    if ((t & 63) == 0) wmax[t >> 6] = pk;
    __syncthreads();
    if (t == 0) {
        unsigned long long m0 = wmax[0];
        #pragma unroll
        for (int i2 = 1; i2 < 4; ++i2) if (wmax[i2] > m0) m0 = wmax[i2];
        atomicMax(&argz[b], m0);
    }
}

// ---------------------------------------------------------------------------
extern "C" void kernel_launch(void* const* d_in, const int* in_sizes, int n_in,
                              void* d_out, int out_size, void* d_ws, size_t ws_size,
                              hipStream_t stream)
{
    const float* dec  = (const float*)d_in[0];
    const float* hid  = (const float*)d_in[1];
    const float* enc  = (const float*)d_in[2];
    const int*   ids  = (const int*)d_in[3];
    const float* emb  = (const float*)d_in[5];
    const float* wih  = (const float*)d_in[6];
    const float* whh  = (const float*)d_in[7];
    const float* bih  = (const float*)d_in[8];
    const float* bhh  = (const float*)d_in[9];
    const float* wgen = (const float*)d_in[10];
    const float* bgen = (const float*)d_in[11];
    float* out = (float*)d_out;

    const int B = 32;
    const int J = in_sizes[0] / (B * D);           // 4
    const int V = in_sizes[5] / D;                 // 30522
    const int K = out_size / (B * J * V);          // 8
    const long JKV = (long)J * K * V;
    const int NVB = (V + 63) / 64;                 // 477

    // workspace carve
    char* w = (char*)d_ws;
    unsigned long long* argpack = (unsigned long long*)w; w += 1024; // 2 x 32
    float* gT        = (float*)w;  w += (size_t)4608 * 32 * 4;
    float* dpartT    = (float*)w;  w += (size_t)32 * 512 * 4;
    float* logitw    = (float*)w;  w += (size_t)B * XX * 4;
    float* penc      = (float*)w;  w += (size_t)B * XX * 4;
    float* pgen_part = (float*)w;  w += (size_t)B * 96 * 4;
    float* h0        = (float*)w;  w += (size_t)B * D * 4;
    float* h1        = (float*)w;  w += (size_t)B * D * 4;
    __bf16* hbf      = (__bf16*)w; w += (size_t)B * D * 2;
    __bf16* embbf    = (__bf16*)w; w += (size_t)V * D * 2;

    const int n8 = V * D / 8;
    k_cvt<<<dim3((n8 + 255) / 256), dim3(256), 0, stream>>>(emb, embbf, n8);
    k_penc<<<dim3(128), dim3(256), 0, stream>>>(enc, wgen, penc);

    int step = 0;
    for (int j = 0; j < J; ++j) {
        for (int kk = 0; kk < K; ++kk) {
            const int cur = step & 1;
            float* hout = (cur == 0) ? h0 : h1;
            const float* hin = (step == 0) ? hid : ((((step - 1) & 1) == 0) ? h0 : h1);
            const float* xbase;
            long xbs;
            const unsigned long long* toks;
            if (kk == 0) {
                xbase = dec + (size_t)j * D;
                xbs = (long)J * D;
                toks = nullptr;
            } else {
                xbase = emb;
                xbs = D;
                toks = argpack + ((step - 1) & 1) * 32;
            }
            unsigned long long* argz = argpack + cur * 32;
            const long outoff = (long)(j * K + kk) * V;

            k_gates<<<dim3(576), dim3(256), 0, stream>>>(
                xbase, xbs, toks, hin, wih, whh, gT);
            k_comb<<<dim3(96), dim3(256), 0, stream>>>(
                gT, bih, bhh, hin, xbase, xbs, toks, wgen, hout, hbf,
                pgen_part, argz);
            k_mid<<<dim3(NVB + NLG), dim3(256), 0, stream>>>(
                hout, hbf, embbf, enc, ids, out, outoff, JKV,
                dpartT, logitw, V, NVB);
            k_fin<<<dim3(256), dim3(256), 0, stream>>>(
                out, outoff, JKV, dpartT, NVB, logitw, penc, pgen_part,
                bgen, ids, argz, V);
            ++step;
        }
    }
}